// Round 8
// baseline (59.741 us; speedup 1.0000x reference)
//
#include <hip/hip_runtime.h>
#include <math.h>

#define BB 4
#define CC 128
#define KK 32
#define NN 4096
#define NSL 64   // 64-pixel slices

// ---------------------------------------------------------------------------
// K1: fused wt-precompute + logits + softmax + sa + pnum/pden partials.
// grid (64 slices, 4 b) x 1024 threads (16 waves) -> 16 waves/CU.
//  - no x LDS stage: logits read x coalesced from global (warms L1 for pnum)
//  - wt table per block in LDS (16 kpairs x 128 c, float4), ck via wave shuffle
//  - logits: thread = (1 px, 2 k); per c: 1 scalar x + 1 broadcast wt4 + 4 FMA
//  - softmax: waves 0..7, 8 lanes per pixel, shuffle reduce (verified R5-R7)
//  - pnum GEMM: thread = (1 k, 4 c); st from LDS b128, x from L1 float4
// ---------------------------------------------------------------------------
__launch_bounds__(1024, 4)
__global__ void k_A(const float* __restrict__ x, const float* __restrict__ anchor,
                    const float* __restrict__ sigp, float* __restrict__ sa,
                    float* __restrict__ pnum, float* __restrict__ pden) {
  const int b  = blockIdx.y, s = blockIdx.x;
  const int n0 = s * 64;
  const int t  = threadIdx.x;
  const int lane = t & 63;
  const int w  = __builtin_amdgcn_readfirstlane(t >> 6);  // wave 0..15

  __shared__ float4 wt4[16][129];   // [kpair][c] {w2_0,aw_0,w2_1,aw_1}  33 KB
  __shared__ float  lgT[64][36];    // logits [px][k]                    9.2 KB
  __shared__ float  stK[KK][68];    // soft-assign [k][px]               8.7 KB
  __shared__ float  ckL[KK];
  __shared__ float  pdenP[8][36];

  // ---- wt table + ck: wave w owns kpair kp=w; lane covers 2 c's
  {
    const int kp = w;                 // 0..15 (one kpair per wave)
    const int k0 = kp * 2, k1 = k0 + 1;
    float s0 = 0.f, s1 = 0.f;
#pragma unroll
    for (int e = 0; e < 2; e++) {
      int c = lane * 2 + e;
      float sp0 = sigp[k0 * CC + c], sp1 = sigp[k1 * CC + c];
      float a0  = anchor[k0 * CC + c], a1 = anchor[k1 * CC + c];
      float sg0 = 1.0f / (1.0f + expf(-sp0));
      float sg1 = 1.0f / (1.0f + expf(-sp1));
      float iv0 = 1.0f / (sg0 + 1e-7f), iv1 = 1.0f / (sg1 + 1e-7f);
      float w20 = iv0 * iv0, w21 = iv1 * iv1;
      wt4[kp][c] = make_float4(w20, -2.0f * a0 * w20, w21, -2.0f * a1 * w21);
      s0 = fmaf(a0 * a0, w20, s0);
      s1 = fmaf(a1 * a1, w21, s1);
    }
#pragma unroll
    for (int d = 1; d < 64; d <<= 1) {
      s0 += __shfl_xor(s0, d);
      s1 += __shfl_xor(s1, d);
    }
    if (lane == 0) { ckL[k0] = s0; ckL[k1] = s1; }
  }
  __syncthreads();

  // ---- logits: thread = (px = lane, kpair = w); x from global (coalesced)
  {
    const int p = lane, kp = w;
    float l0 = 0.f, l1 = 0.f;
    const float* xp = x + (size_t)b * CC * NN + n0 + p;
    for (int c = 0; c < CC; c++) {
      float xv = xp[(size_t)c * NN];
      float4 wv = wt4[kp][c];                       // wave-uniform broadcast
      l0 = fmaf(xv, fmaf(xv, wv.x, wv.y), l0);
      l1 = fmaf(xv, fmaf(xv, wv.z, wv.w), l1);
    }
    *(float2*)&lgT[p][kp * 2] = make_float2(l0, l1);
  }
  __syncthreads();

  // ---- softmax over k (waves 0..7): 8 lanes per pixel, shuffle reduce
  if (t < 512) {
    const int p  = w * 8 + (lane >> 3);
    const int kq = lane & 7;
    float4 lg  = *(float4*)&lgT[p][kq * 4];
    float4 ckv = *(float4*)&ckL[kq * 4];
    float4 lv;
    lv.x = -0.5f * (lg.x + ckv.x);
    lv.y = -0.5f * (lg.y + ckv.y);
    lv.z = -0.5f * (lg.z + ckv.z);
    lv.w = -0.5f * (lg.w + ckv.w);
    float m = fmaxf(fmaxf(lv.x, lv.y), fmaxf(lv.z, lv.w));
    m = fmaxf(m, __shfl_xor(m, 1));
    m = fmaxf(m, __shfl_xor(m, 2));
    m = fmaxf(m, __shfl_xor(m, 4));
    float e0 = __expf(lv.x - m), e1 = __expf(lv.y - m);
    float e2 = __expf(lv.z - m), e3 = __expf(lv.w - m);
    float sum = e0 + e1 + e2 + e3;
    sum += __shfl_xor(sum, 1);
    sum += __shfl_xor(sum, 2);
    sum += __shfl_xor(sum, 4);
    float rs = 1.0f / sum;
    e0 *= rs; e1 *= rs; e2 *= rs; e3 *= rs;
    stK[kq * 4 + 0][p] = e0;
    stK[kq * 4 + 1][p] = e1;
    stK[kq * 4 + 2][p] = e2;
    stK[kq * 4 + 3][p] = e3;
    float p0 = e0, p1 = e1, p2 = e2, p3 = e3;
    p0 += __shfl_xor(p0, 8);  p1 += __shfl_xor(p1, 8);
    p2 += __shfl_xor(p2, 8);  p3 += __shfl_xor(p3, 8);
    p0 += __shfl_xor(p0, 16); p1 += __shfl_xor(p1, 16);
    p2 += __shfl_xor(p2, 16); p3 += __shfl_xor(p3, 16);
    p0 += __shfl_xor(p0, 32); p1 += __shfl_xor(p1, 32);
    p2 += __shfl_xor(p2, 32); p3 += __shfl_xor(p3, 32);
    if (lane < 8) {
      pdenP[w][lane * 4 + 0] = p0;
      pdenP[w][lane * 4 + 1] = p1;
      pdenP[w][lane * 4 + 2] = p2;
      pdenP[w][lane * 4 + 3] = p3;
    }
  }
  __syncthreads();

  // ---- pden write
  if (t < KK) {
    float d = 0.f;
#pragma unroll
    for (int ww = 0; ww < 8; ww++) d += pdenP[ww][t];
    pden[((size_t)b * NSL + s) * KK + t] = d;
  }

  // ---- sa write: thread (k=t>>4, j4=t&15), coalesced float4 (waves 0..7)
  if (t < 512) {
    const int k = t >> 4, j4 = t & 15;
    float4 v = *(float4*)&stK[k][4 * j4];
    *(float4*)(sa + ((size_t)b * KK + k) * NN + n0 + 4 * j4) = v;
  }

  // ---- pnum GEMM: thread (k=t&31, cg=t>>5 -> 4 c) over 64 n
  {
    const int k = t & 31, cg = t >> 5;   // cg 0..31
    float acc[4];
#pragma unroll
    for (int i = 0; i < 4; i++) acc[i] = 0.f;
    const float* xb = x + (size_t)(b * CC + cg * 4) * NN + n0;
    for (int j4 = 0; j4 < 16; j4++) {
      float4 sv = *(float4*)&stK[k][4 * j4];
#pragma unroll
      for (int i = 0; i < 4; i++) {
        float4 xr = *(const float4*)(xb + (size_t)i * NN + 4 * j4);
        acc[i] = fmaf(sv.x, xr.x, acc[i]);
        acc[i] = fmaf(sv.y, xr.y, acc[i]);
        acc[i] = fmaf(sv.z, xr.z, acc[i]);
        acc[i] = fmaf(sv.w, xr.w, acc[i]);
      }
    }
    float* pp = pnum + (((size_t)b * NSL + s) * KK + k) * CC + cg * 4;
    *(float4*)pp = make_float4(acc[0], acc[1], acc[2], acc[3]);
  }
}

// ---------------------------------------------------------------------------
// K2: full-occupancy reduce of pnum/pden -> unnormalized nodes + n1sq.
// grid = 64 blocks x 256; one thread per (b,k,c). (verified R5-R7)
// ---------------------------------------------------------------------------
__launch_bounds__(256)
__global__ void k_red(const float* __restrict__ pnum, const float* __restrict__ pden,
                      const float* __restrict__ sigp, const float* __restrict__ anchor,
                      float* __restrict__ nodes, float* __restrict__ n1sq) {
  const int t = threadIdx.x;
  const int g = blockIdx.x * 256 + t;
  const int c = g & 127, k = (g >> 7) & 31, b = g >> 12;

  float dk = 0.0f;
#pragma unroll 8
  for (int s = 0; s < NSL; s++) dk += pden[((size_t)b * NSL + s) * KK + k];

  float q = 0.0f;
#pragma unroll 8
  for (int s = 0; s < NSL; s++)
    q += pnum[(((size_t)b * NSL + s) * KK + k) * CC + c];

  const int idx = k * CC + c;
  float sg = 1.0f / (1.0f + expf(-sigp[idx]));
  float iv = 1.0f / (sg + 1e-7f);
  float val = iv * (q - anchor[idx] * dk) / (dk + 1e-7f);
  nodes[((size_t)b * KK + k) * CC + c] = val;

  __shared__ float red[256];
  red[t] = val * val;
  __syncthreads();
  for (int sft = 64; sft > 0; sft >>= 1) {
    if ((t & 127) < sft) red[t] += red[t + sft];
    __syncthreads();
  }
  if ((t & 127) == 0) n1sq[b * KK + k] = red[t];
}

// ---------------------------------------------------------------------------
// K3: normalize + adj softmax + support GEMM + GB. 4 blocks x 1024 threads.
// (verified R6/R7)
// ---------------------------------------------------------------------------
__launch_bounds__(1024)
__global__ void k_gcn2(const float* __restrict__ nodes, const float* __restrict__ n1sq,
                       const float* __restrict__ W, float* __restrict__ GB) {
  const int b = blockIdx.x;
  const int t = threadIdx.x;
  __shared__ float flat[KK * CC];
  __shared__ float sup[KK][130];
  __shared__ float adjm[KK][33];
  __shared__ float n1v[KK], nsq[KK];
  __shared__ float n2s;

  const int k = t >> 5, cq = t & 31;
  float4 val = ((const float4*)(nodes + (size_t)b * KK * CC))[k * 32 + cq];

  if (t < KK) {
    float s2 = n1sq[b * KK + t];
    float n1 = fmaxf(sqrtf(s2), 1e-12f);
    n1v[t] = n1;
    nsq[t] = s2 / (n1 * n1);
  }
  __syncthreads();
  if (t == 0) {
    float tot = 0.0f;
#pragma unroll
    for (int kk = 0; kk < KK; kk++) tot += nsq[kk];
    n2s = fmaxf(sqrtf(tot), 1e-12f);
  }
  __syncthreads();
  {
    float sc = 1.0f / (n1v[k] * n2s);
    val.x *= sc; val.y *= sc; val.z *= sc; val.w *= sc;
    ((float4*)flat)[k * 32 + cq] = val;
  }
  __syncthreads();

  {  // adj[k2][l] = sum_i flat[i*32+k2]*flat[i*32+l]
    const int k2 = t >> 5, l = t & 31;
    float a = 0.0f;
#pragma unroll 8
    for (int i = 0; i < CC; i++)
      a = fmaf(flat[i * KK + k2], flat[i * KK + l], a);
    adjm[k2][l] = a;
  }
  __syncthreads();
  if (t < KK) {  // row softmax
    float m = -1e30f;
#pragma unroll
    for (int l = 0; l < KK; l++) m = fmaxf(m, adjm[t][l]);
    float s2 = 0.0f;
#pragma unroll
    for (int l = 0; l < KK; l++) { float e = __expf(adjm[t][l] - m); adjm[t][l] = e; s2 += e; }
    float r = 1.0f / s2;
#pragma unroll
    for (int l = 0; l < KK; l++) adjm[t][l] *= r;
  }
  __syncthreads();

  const int d = t & 127, lg = t >> 7;
  float sacc[4] = {0.0f, 0.0f, 0.0f, 0.0f};
  for (int c = 0; c < CC; c++) {
    float wv = W[c * CC + d];
#pragma unroll
    for (int j = 0; j < 4; j++)
      sacc[j] = fmaf(flat[c * KK + lg + 8 * j], wv, sacc[j]);
  }
#pragma unroll
  for (int j = 0; j < 4; j++) sup[lg + 8 * j][d] = sacc[j];
  __syncthreads();

#pragma unroll
  for (int j = 0; j < 4; j++) {
    int kk = lg + 8 * j;
    float g = 0.0f;
#pragma unroll
    for (int l = 0; l < KK; l++) g = fmaf(adjm[kk][l], sup[l][d], g);
    GB[((size_t)b * CC + d) * KK + kk] = fmaxf(g, 0.0f);
  }
}

// ---------------------------------------------------------------------------
// K4: out[b][c][n] = sum_k GB[b][c][k] * sa[b][k][n]
// grid (64 n-slices, 4 c-quarters, B) x 256 -> 1024 blocks, 16 waves/CU.
// ---------------------------------------------------------------------------
__launch_bounds__(256)
__global__ void k_proj(const float* __restrict__ GB, const float* __restrict__ sa,
                       float* __restrict__ out) {
  const int b  = blockIdx.z, cqt = blockIdx.y;
  const int n0 = blockIdx.x * 64;
  const int t  = threadIdx.x;
  const int nl = t & 63;
  const int cg = __builtin_amdgcn_readfirstlane(t >> 6);  // 0..3
  const int c0 = cqt * 32 + cg * 8;

  float sreg[KK];
  const float* spt = sa + (size_t)b * KK * NN + n0 + nl;
#pragma unroll
  for (int k = 0; k < KK; k++) sreg[k] = spt[(size_t)k * NN];

  const float* gp = GB + ((size_t)b * CC + c0) * KK;
  float* op = out + ((size_t)b * CC + c0) * NN + n0 + nl;
#pragma unroll
  for (int ci = 0; ci < 8; ci++) {
    float acc = 0.0f;
#pragma unroll
    for (int k = 0; k < KK; k++) acc = fmaf(gp[ci * KK + k], sreg[k], acc);
    op[(size_t)ci * NN] = acc;
  }
}

// ---------------------------------------------------------------------------
extern "C" void kernel_launch(void* const* d_in, const int* in_sizes, int n_in,
                              void* d_out, int out_size, void* d_ws, size_t ws_size,
                              hipStream_t stream) {
  const float* x      = (const float*)d_in[0];
  const float* anchor = (const float*)d_in[1];
  const float* sigp   = (const float*)d_in[2];
  const float* W      = (const float*)d_in[3];
  float* out = (float*)d_out;

  float* ws    = (float*)d_ws;
  float* pden  = ws;               //    8192
  float* pnum  = ws + 8192;        // 1048576
  float* nodes = ws + 1056768;     //   16384
  float* n1sq  = ws + 1073152;     //     128
  float* GB    = ws + 1073280;     //   16384
  float* sa    = ws + 1089664;     //  524288

  k_A   <<<dim3(NSL, BB),     dim3(1024), 0, stream>>>(x, anchor, sigp, sa, pnum, pden);
  k_red <<<dim3(64),          dim3(256),  0, stream>>>(pnum, pden, sigp, anchor, nodes, n1sq);
  k_gcn2<<<dim3(BB),          dim3(1024), 0, stream>>>(nodes, n1sq, W, GB);
  k_proj<<<dim3(64, 4, BB),   dim3(256),  0, stream>>>(GB, sa, out);
}

// Round 9
// 54.177 us; speedup vs baseline: 1.1027x; 1.1027x over previous
//
#include <hip/hip_runtime.h>
#include <math.h>

#define BB 4
#define CC 128
#define KK 32
#define NN 4096
#define NSL 64   // 64-pixel slices

// ---------------------------------------------------------------------------
// K1: fused wt-precompute + logits + softmax + sa + pnum/pden partials.
// grid (64 slices, 4 b) x 1024 threads (16 waves), 64 px per block.
//  - x tile staged to LDS once (32 KB, float4)
//  - wt table per block in LDS (16 kpairs x 128 c float4), ck via wave shuffle
//  - logits: register-tiled GEMM: thread = (4 px, 2 k, 32 c); per c:
//      2 ds_read_b128 + 16 FMA (Horner); partials combined in softmax
//  - softmax: waves 0..7, 8 lanes per pixel, shuffle reduce (verified R5-R8)
//  - pnum GEMM: thread = (1 k, 4 c); st from LDS b128, x from L1 float4 (R8)
// ---------------------------------------------------------------------------
__launch_bounds__(1024, 4)
__global__ void k_A(const float* __restrict__ x, const float* __restrict__ anchor,
                    const float* __restrict__ sigp, float* __restrict__ sa,
                    float* __restrict__ pnum, float* __restrict__ pden) {
  const int b  = blockIdx.y, s = blockIdx.x;
  const int n0 = s * 64;
  const int t  = threadIdx.x;
  const int lane = t & 63;
  const int w  = __builtin_amdgcn_readfirstlane(t >> 6);  // wave 0..15

  __shared__ float  xt[CC][68];      // x tile [c][px]                 34.8 KB
  __shared__ float4 wt4[16][129];    // [kpair][c] {w2_0,aw_0,w2_1,aw_1} 33 KB
  __shared__ float  plg[4][64][36];  // logit partials [ch][px][k]     36.9 KB
  __shared__ float  stK[KK][68];     // soft-assign [k][px]             8.7 KB
  __shared__ float  ckL[KK];
  __shared__ float  pdenP[8][36];

  // ---- stage x tile (32 KB): 2 float4 per thread, coalesced
  {
#pragma unroll
    for (int e = 0; e < 2; e++) {
      int i = t + e * 1024;          // i in [0, 2048)
      int c = i >> 4, pq = i & 15;
      float4 v = *(const float4*)(x + ((size_t)b * CC + c) * NN + n0 + 4 * pq);
      *(float4*)&xt[c][4 * pq] = v;
    }
  }

  // ---- wt table + ck: wave w owns kpair kp=w; lane covers 2 c's (R8 verified)
  {
    const int kp = w;
    const int k0 = kp * 2, k1 = k0 + 1;
    float s0 = 0.f, s1 = 0.f;
#pragma unroll
    for (int e = 0; e < 2; e++) {
      int c = lane * 2 + e;
      float sp0 = sigp[k0 * CC + c], sp1 = sigp[k1 * CC + c];
      float a0  = anchor[k0 * CC + c], a1 = anchor[k1 * CC + c];
      float sg0 = 1.0f / (1.0f + expf(-sp0));
      float sg1 = 1.0f / (1.0f + expf(-sp1));
      float iv0 = 1.0f / (sg0 + 1e-7f), iv1 = 1.0f / (sg1 + 1e-7f);
      float w20 = iv0 * iv0, w21 = iv1 * iv1;
      wt4[kp][c] = make_float4(w20, -2.0f * a0 * w20, w21, -2.0f * a1 * w21);
      s0 = fmaf(a0 * a0, w20, s0);
      s1 = fmaf(a1 * a1, w21, s1);
    }
#pragma unroll
    for (int d = 1; d < 64; d <<= 1) {
      s0 += __shfl_xor(s0, d);
      s1 += __shfl_xor(s1, d);
    }
    if (lane == 0) { ckL[k0] = s0; ckL[k1] = s1; }
  }
  __syncthreads();

  // ---- logits GEMM: thread = (px4 = t&15, kp = (t>>4)&15, ch = t>>8)
  {
    const int px4 = t & 15, kp = (t >> 4) & 15, ch = t >> 8;
    float acc[4][2];
#pragma unroll
    for (int i = 0; i < 4; i++) { acc[i][0] = 0.f; acc[i][1] = 0.f; }
    for (int c0 = 0; c0 < 32; c0++) {
      const int c = ch * 32 + c0;
      float4 xv = *(const float4*)&xt[c][px4 * 4];
      float4 wv = wt4[kp][c];
#pragma unroll
      for (int i = 0; i < 4; i++) {
        float xs = (&xv.x)[i];
        acc[i][0] = fmaf(xs, fmaf(xs, wv.x, wv.y), acc[i][0]);
        acc[i][1] = fmaf(xs, fmaf(xs, wv.z, wv.w), acc[i][1]);
      }
    }
#pragma unroll
    for (int i = 0; i < 4; i++) {
      plg[ch][px4 * 4 + i][kp * 2 + 0] = acc[i][0];
      plg[ch][px4 * 4 + i][kp * 2 + 1] = acc[i][1];
    }
  }
  __syncthreads();

  // ---- softmax over k (waves 0..7): combine 4 c-chunk partials + ck
  if (t < 512) {
    const int p  = w * 8 + (lane >> 3);
    const int kq = lane & 7;
    float4 l0  = *(float4*)&plg[0][p][kq * 4];
    float4 l1  = *(float4*)&plg[1][p][kq * 4];
    float4 l2  = *(float4*)&plg[2][p][kq * 4];
    float4 l3  = *(float4*)&plg[3][p][kq * 4];
    float4 ckv = *(float4*)&ckL[kq * 4];
    float4 lv;
    lv.x = -0.5f * (l0.x + l1.x + l2.x + l3.x + ckv.x);
    lv.y = -0.5f * (l0.y + l1.y + l2.y + l3.y + ckv.y);
    lv.z = -0.5f * (l0.z + l1.z + l2.z + l3.z + ckv.z);
    lv.w = -0.5f * (l0.w + l1.w + l2.w + l3.w + ckv.w);
    float m = fmaxf(fmaxf(lv.x, lv.y), fmaxf(lv.z, lv.w));
    m = fmaxf(m, __shfl_xor(m, 1));
    m = fmaxf(m, __shfl_xor(m, 2));
    m = fmaxf(m, __shfl_xor(m, 4));
    float e0 = __expf(lv.x - m), e1 = __expf(lv.y - m);
    float e2 = __expf(lv.z - m), e3 = __expf(lv.w - m);
    float sum = e0 + e1 + e2 + e3;
    sum += __shfl_xor(sum, 1);
    sum += __shfl_xor(sum, 2);
    sum += __shfl_xor(sum, 4);
    float rs = 1.0f / sum;
    e0 *= rs; e1 *= rs; e2 *= rs; e3 *= rs;
    stK[kq * 4 + 0][p] = e0;
    stK[kq * 4 + 1][p] = e1;
    stK[kq * 4 + 2][p] = e2;
    stK[kq * 4 + 3][p] = e3;
    float p0 = e0, p1 = e1, p2 = e2, p3 = e3;
    p0 += __shfl_xor(p0, 8);  p1 += __shfl_xor(p1, 8);
    p2 += __shfl_xor(p2, 8);  p3 += __shfl_xor(p3, 8);
    p0 += __shfl_xor(p0, 16); p1 += __shfl_xor(p1, 16);
    p2 += __shfl_xor(p2, 16); p3 += __shfl_xor(p3, 16);
    p0 += __shfl_xor(p0, 32); p1 += __shfl_xor(p1, 32);
    p2 += __shfl_xor(p2, 32); p3 += __shfl_xor(p3, 32);
    if (lane < 8) {
      pdenP[w][lane * 4 + 0] = p0;
      pdenP[w][lane * 4 + 1] = p1;
      pdenP[w][lane * 4 + 2] = p2;
      pdenP[w][lane * 4 + 3] = p3;
    }
  }
  __syncthreads();

  // ---- pden write
  if (t < KK) {
    float d = 0.f;
#pragma unroll
    for (int ww = 0; ww < 8; ww++) d += pdenP[ww][t];
    pden[((size_t)b * NSL + s) * KK + t] = d;
  }

  // ---- sa write (waves 0..7): coalesced float4
  if (t < 512) {
    const int k = t >> 4, j4 = t & 15;
    float4 v = *(float4*)&stK[k][4 * j4];
    *(float4*)(sa + ((size_t)b * KK + k) * NN + n0 + 4 * j4) = v;
  }

  // ---- pnum GEMM: thread (k=t&31, cg=t>>5 -> 4 c) over 64 n (R8 verified)
  {
    const int k = t & 31, cg = t >> 5;
    float acc[4];
#pragma unroll
    for (int i = 0; i < 4; i++) acc[i] = 0.f;
    const float* xb = x + (size_t)(b * CC + cg * 4) * NN + n0;
    for (int j4 = 0; j4 < 16; j4++) {
      float4 sv = *(float4*)&stK[k][4 * j4];
#pragma unroll
      for (int i = 0; i < 4; i++) {
        float4 xr = *(const float4*)(xb + (size_t)i * NN + 4 * j4);
        acc[i] = fmaf(sv.x, xr.x, acc[i]);
        acc[i] = fmaf(sv.y, xr.y, acc[i]);
        acc[i] = fmaf(sv.z, xr.z, acc[i]);
        acc[i] = fmaf(sv.w, xr.w, acc[i]);
      }
    }
    float* pp = pnum + (((size_t)b * NSL + s) * KK + k) * CC + cg * 4;
    *(float4*)pp = make_float4(acc[0], acc[1], acc[2], acc[3]);
  }
}

// ---------------------------------------------------------------------------
// K2: full-occupancy reduce of pnum/pden -> unnormalized nodes + n1sq.
// grid = 64 blocks x 256; one thread per (b,k,c). (verified R5-R8)
// ---------------------------------------------------------------------------
__launch_bounds__(256)
__global__ void k_red(const float* __restrict__ pnum, const float* __restrict__ pden,
                      const float* __restrict__ sigp, const float* __restrict__ anchor,
                      float* __restrict__ nodes, float* __restrict__ n1sq) {
  const int t = threadIdx.x;
  const int g = blockIdx.x * 256 + t;
  const int c = g & 127, k = (g >> 7) & 31, b = g >> 12;

  float dk = 0.0f;
#pragma unroll 8
  for (int s = 0; s < NSL; s++) dk += pden[((size_t)b * NSL + s) * KK + k];

  float q = 0.0f;
#pragma unroll 8
  for (int s = 0; s < NSL; s++)
    q += pnum[(((size_t)b * NSL + s) * KK + k) * CC + c];

  const int idx = k * CC + c;
  float sg = 1.0f / (1.0f + expf(-sigp[idx]));
  float iv = 1.0f / (sg + 1e-7f);
  float val = iv * (q - anchor[idx] * dk) / (dk + 1e-7f);
  nodes[((size_t)b * KK + k) * CC + c] = val;

  __shared__ float red[256];
  red[t] = val * val;
  __syncthreads();
  for (int sft = 64; sft > 0; sft >>= 1) {
    if ((t & 127) < sft) red[t] += red[t + sft];
    __syncthreads();
  }
  if ((t & 127) == 0) n1sq[b * KK + k] = red[t];
}

// ---------------------------------------------------------------------------
// K3 (fused GCN + projection): grid (64 slices, 4 b) x 1024 threads.
// Each block redundantly computes the tiny GCN (normalize, adj softmax,
// support GEMM, GB -> LDS), then projects its own 64-px slice:
//   out[b][c][n] = sum_k gbL[c][k] * sa[b][k][n]
// ---------------------------------------------------------------------------
__launch_bounds__(1024, 4)
__global__ void k_BC(const float* __restrict__ nodes, const float* __restrict__ n1sq,
                     const float* __restrict__ W, const float* __restrict__ sa,
                     float* __restrict__ out) {
  const int b = blockIdx.y, s = blockIdx.x;
  const int n0 = s * 64;
  const int t = threadIdx.x;
  __shared__ float flat[KK * CC];
  __shared__ float sup[KK][130];
  __shared__ float adjm[KK][33];
  __shared__ float gbL[CC][KK + 1];
  __shared__ float n1v[KK], nsq[KK];
  __shared__ float n2s;

  const int k = t >> 5, cq = t & 31;
  float4 val = ((const float4*)(nodes + (size_t)b * KK * CC))[k * 32 + cq];

  if (t < KK) {
    float s2 = n1sq[b * KK + t];
    float n1 = fmaxf(sqrtf(s2), 1e-12f);
    n1v[t] = n1;
    nsq[t] = s2 / (n1 * n1);
  }
  __syncthreads();
  if (t == 0) {
    float tot = 0.0f;
#pragma unroll
    for (int kk = 0; kk < KK; kk++) tot += nsq[kk];
    n2s = fmaxf(sqrtf(tot), 1e-12f);
  }
  __syncthreads();
  {
    float sc = 1.0f / (n1v[k] * n2s);
    val.x *= sc; val.y *= sc; val.z *= sc; val.w *= sc;
    ((float4*)flat)[k * 32 + cq] = val;
  }
  __syncthreads();

  {  // adj[k2][l] = sum_i flat[i*32+k2]*flat[i*32+l]
    const int k2 = t >> 5, l = t & 31;
    float a = 0.0f;
#pragma unroll 8
    for (int i = 0; i < CC; i++)
      a = fmaf(flat[i * KK + k2], flat[i * KK + l], a);
    adjm[k2][l] = a;
  }
  __syncthreads();
  if (t < KK) {  // row softmax
    float m = -1e30f;
#pragma unroll
    for (int l = 0; l < KK; l++) m = fmaxf(m, adjm[t][l]);
    float s2 = 0.0f;
#pragma unroll
    for (int l = 0; l < KK; l++) { float e = __expf(adjm[t][l] - m); adjm[t][l] = e; s2 += e; }
    float r = 1.0f / s2;
#pragma unroll
    for (int l = 0; l < KK; l++) adjm[t][l] *= r;
  }
  __syncthreads();

  {  // support[l][d] = sum_c flat[c*32+l] * W[c*128+d]
    const int d = t & 127, lg = t >> 7;
    float sacc[4] = {0.0f, 0.0f, 0.0f, 0.0f};
    for (int c = 0; c < CC; c++) {
      float wv = W[c * CC + d];
#pragma unroll
      for (int j = 0; j < 4; j++)
        sacc[j] = fmaf(flat[c * KK + lg + 8 * j], wv, sacc[j]);
    }
#pragma unroll
    for (int j = 0; j < 4; j++) sup[lg + 8 * j][d] = sacc[j];
  }
  __syncthreads();

  {  // gbL[d][kk] = relu( sum_l adjm[kk][l] * sup[l][d] )
    const int d = t & 127, lg = t >> 7;
#pragma unroll
    for (int j = 0; j < 4; j++) {
      int kk = lg + 8 * j;
      float g = 0.0f;
#pragma unroll
      for (int l = 0; l < KK; l++) g = fmaf(adjm[kk][l], sup[l][d], g);
      gbL[d][kk] = fmaxf(g, 0.0f);
    }
  }
  __syncthreads();

  // ---- projection: thread (nl = t&63, cw = t>>6 -> 8 c's)
  {
    const int nl = t & 63, cw = t >> 6;
    const int c0 = cw * 8;
    float sreg[KK];
    const float* spt = sa + (size_t)b * KK * NN + n0 + nl;
#pragma unroll
    for (int kk = 0; kk < KK; kk++) sreg[kk] = spt[(size_t)kk * NN];

    float* op = out + ((size_t)b * CC + c0) * NN + n0 + nl;
#pragma unroll
    for (int ci = 0; ci < 8; ci++) {
      float acc = 0.0f;
#pragma unroll
      for (int kk = 0; kk < KK; kk++)
        acc = fmaf(gbL[c0 + ci][kk], sreg[kk], acc);
      op[(size_t)ci * NN] = acc;
    }
  }
}

// ---------------------------------------------------------------------------
extern "C" void kernel_launch(void* const* d_in, const int* in_sizes, int n_in,
                              void* d_out, int out_size, void* d_ws, size_t ws_size,
                              hipStream_t stream) {
  const float* x      = (const float*)d_in[0];
  const float* anchor = (const float*)d_in[1];
  const float* sigp   = (const float*)d_in[2];
  const float* W      = (const float*)d_in[3];
  float* out = (float*)d_out;

  float* ws    = (float*)d_ws;
  float* pden  = ws;               //    8192
  float* pnum  = ws + 8192;        // 1048576
  float* nodes = ws + 1056768;     //   16384
  float* n1sq  = ws + 1073152;     //     128
  float* sa    = ws + 1073280;     //  524288

  k_A  <<<dim3(NSL, BB), dim3(1024), 0, stream>>>(x, anchor, sigp, sa, pnum, pden);
  k_red<<<dim3(64),      dim3(256),  0, stream>>>(pnum, pden, sigp, anchor, nodes, n1sq);
  k_BC <<<dim3(NSL, BB), dim3(1024), 0, stream>>>(nodes, n1sq, W, sa, out);
}